// Round 12
// baseline (241.230 us; speedup 1.0000x reference)
//
#include <hip/hip_runtime.h>

#define DIM 64
#define PBITS 6
#define PART_BUCKETS 64       // buckets per partition
#define NPART_MAX 2368        // >= ceil(150016/64)=2344
#define EPT 32                // edges per thread, pass1
#define EPB (EPT * 256)       // 8192 edges per block, pass1
#define CAP 4096              // max records per partition (avg 2560 entity, +30 sigma)

// ---------------- fallback (round-1) atomic kernel ----------------
__global__ void coo_scatter_kernel(const float* __restrict__ user_emb,
                                   const float* __restrict__ entity_emb,
                                   const int* __restrict__ rows,
                                   const int* __restrict__ cols,
                                   const float* __restrict__ vals,
                                   float* __restrict__ entity_agg,
                                   float* __restrict__ user_agg,
                                   int nnz) {
    long long tid = (long long)blockIdx.x * blockDim.x + threadIdx.x;
    long long total = (long long)nnz * DIM;
    if (tid >= total) return;
    int edge = (int)(tid >> 6);
    int d = (int)(tid & 63);
    int r = rows[edge];
    int c = cols[edge];
    float v = vals[edge];
    atomicAdd(&entity_agg[c * DIM + d], v * user_emb[r * DIM + d]);
    atomicAdd(&user_agg[r * DIM + d], v * entity_emb[c * DIM + d]);
}

// record: uint2 { meta, valbits }; meta = (local6<<18) | (side<<17) | src
// bucket = partition*64 + local6. side 0: gather user_emb; side 1: entity_emb.

// pass0: per-partition histogram (LDS-staged)
__global__ __launch_bounds__(256) void pass0_hist(const int* __restrict__ rows,
                                                  const int* __restrict__ cols,
                                                  int* __restrict__ pcnt,
                                                  int ne, int nnz, int npart) {
    __shared__ int h[NPART_MAX];
    for (int t = threadIdx.x; t < npart; t += 256) h[t] = 0;
    __syncthreads();
    for (int i = blockIdx.x * blockDim.x + threadIdx.x; i < nnz;
         i += gridDim.x * blockDim.x) {
        int c = cols[i];
        int r = rows[i];
        atomicAdd(&h[c >> PBITS], 1);
        atomicAdd(&h[(ne + r) >> PBITS], 1);
    }
    __syncthreads();
    for (int t = threadIdx.x; t < npart; t += 256)
        if (h[t]) atomicAdd(&pcnt[t], h[t]);
}

// scan over npart partition counts (single block, parallel)
__global__ __launch_bounds__(256) void scan_parts(const int* __restrict__ pcnt,
                                                  int* __restrict__ poffs,
                                                  int* __restrict__ pcursor,
                                                  int* __restrict__ ovfcnt,
                                                  int npart) {
    __shared__ int sh[256];
    int t = threadIdx.x;
    int local[10];
    int s = 0;
#pragma unroll
    for (int j = 0; j < 10; ++j) {
        int idx = t * 10 + j;
        local[j] = (idx < npart) ? pcnt[idx] : 0;
        s += local[j];
    }
    sh[t] = s;
    for (int off = 1; off < 256; off <<= 1) {
        __syncthreads();
        int tmp = (t >= off) ? sh[t - off] : 0;
        __syncthreads();
        sh[t] += tmp;
    }
    __syncthreads();
    int run = sh[t] - s;   // exclusive prefix
#pragma unroll
    for (int j = 0; j < 10; ++j) {
        int idx = t * 10 + j;
        if (idx < npart) {
            poffs[idx] = run;
            pcursor[idx] = run;
            run += local[j];
        }
    }
    if (t == 255) poffs[npart] = sh[255];
    if (t == 0) *ovfcnt = 0;
}

// pass1: two sweeps over this block's edges. Sweep A: LDS histogram.
// Claim one contiguous global chunk per (block, partition). Sweep B:
// rebuild record on the fly (L2-hot re-read) and store at rank.
// All writers of a chunk are one block -> mostly single-L2 full lines.
__global__ __launch_bounds__(256) void pass1_part(const int* __restrict__ rows,
                                                  const int* __restrict__ cols,
                                                  const float* __restrict__ vals,
                                                  int* __restrict__ pcursor,
                                                  uint2* __restrict__ payload,
                                                  int ne, int nnz, int npart) {
    __shared__ int hist[NPART_MAX];
    __shared__ int cur[NPART_MAX];
    __shared__ int gbase[NPART_MAX];
    for (int t = threadIdx.x; t < npart; t += 256) { hist[t] = 0; cur[t] = 0; }
    __syncthreads();

    int base = blockIdx.x * EPB;
#pragma unroll 4
    for (int k = 0; k < EPT; ++k) {
        int i = base + threadIdx.x + k * 256;
        if (i < nnz) {
            atomicAdd(&hist[cols[i] >> PBITS], 1);
            atomicAdd(&hist[(ne + rows[i]) >> PBITS], 1);
        }
    }
    __syncthreads();
    for (int p = threadIdx.x; p < npart; p += 256) {
        int c_ = hist[p];
        if (c_) gbase[p] = atomicAdd(&pcursor[p], c_);
    }
    __syncthreads();
#pragma unroll 4
    for (int k = 0; k < EPT; ++k) {
        int i = base + threadIdx.x + k * 256;
        if (i < nnz) {
            int r = rows[i];
            int c = cols[i];
            unsigned vb = __float_as_uint(vals[i]);
            int b2 = ne + r;
            int p1 = c >> PBITS;
            int p2 = b2 >> PBITS;
            int rank1 = atomicAdd(&cur[p1], 1);
            payload[(size_t)gbase[p1] + rank1] =
                make_uint2(((unsigned)(c & (PART_BUCKETS - 1)) << 18) | (unsigned)r, vb);
            int rank2 = atomicAdd(&cur[p2], 1);
            payload[(size_t)gbase[p2] + rank2] =
                make_uint2(((unsigned)(b2 & (PART_BUCKETS - 1)) << 18) | (1u << 17) | (unsigned)c, vb);
        }
    }
}

// fused sort+agg: one block per partition. Load records to regs, counting
// sort into LDS, then each wave aggregates 16 buckets straight from LDS.
__global__ __launch_bounds__(256) void sort_agg(const float* __restrict__ user_emb,
                                                const float* __restrict__ entity_emb,
                                                const uint2* __restrict__ payload,
                                                const int* __restrict__ poffs,
                                                int* __restrict__ ovfcnt,
                                                int* __restrict__ ovflist,
                                                float* __restrict__ out,
                                                int nb) {
    __shared__ uint2 srec[CAP];                       // 32 KB sorted records
    __shared__ int h[PART_BUCKETS], sc[PART_BUCKETS], cu[PART_BUCKETS];
    int p = blockIdx.x;
    int beg = poffs[p];
    int n = poffs[p + 1] - beg;
    int t = threadIdx.x;
    if (t < PART_BUCKETS) h[t] = 0;
    __syncthreads();

    if (n > CAP) {   // ~30 sigma; zero rows, defer to pass3 atomics
        if (t == 0) {
            int o = atomicAdd(ovfcnt, 1);
            ovflist[o] = p;
        }
        int b0 = p << PBITS;
        for (int e = t; e < PART_BUCKETS * DIM; e += 256) {
            int b = b0 + (e >> 6);
            if (b < nb) out[(size_t)b * DIM + (e & 63)] = 0.f;
        }
        return;
    }

    uint2 rec[CAP / 256];
#pragma unroll
    for (int k = 0; k < CAP / 256; ++k) {
        int idx = t + k * 256;
        if (idx < n) {
            rec[k] = payload[(size_t)beg + idx];
            atomicAdd(&h[(rec[k].x >> 18) & (PART_BUCKETS - 1)], 1);
        }
    }
    __syncthreads();
    if (t == 0) {
        int run = 0;
#pragma unroll
        for (int j = 0; j < PART_BUCKETS; ++j) { sc[j] = run; cu[j] = run; run += h[j]; }
    }
    __syncthreads();
#pragma unroll
    for (int k = 0; k < CAP / 256; ++k) {
        int idx = t + k * 256;
        if (idx < n) {
            int b = (rec[k].x >> 18) & (PART_BUCKETS - 1);
            int rank = atomicAdd(&cu[b], 1);
            srec[rank] = rec[k];
        }
    }
    __syncthreads();

    // phase 2: wave w aggregates buckets [w*16, w*16+16)
    int wid = t >> 6;
    int lane = t & 63;
    int grp = lane >> 4;      // which record of the quad
    int sub = lane & 15;      // float4 slot within the row

    for (int bi = 0; bi < 16; ++bi) {
        int lb = wid * 16 + bi;
        int bucket = (p << PBITS) + lb;
        int rb = sc[lb];
        int cnt = h[lb];

        float ax0 = 0.f, ay0 = 0.f, az0 = 0.f, aw0 = 0.f;
        float ax1 = 0.f, ay1 = 0.f, az1 = 0.f, aw1 = 0.f;

        int i = 0;
        for (; i + 8 <= cnt; i += 8) {
            uint2 rA = srec[rb + i + grp];
            uint2 rB = srec[rb + i + 4 + grp];
            const float* __restrict__ tA = (rA.x & (1u << 17)) ? entity_emb : user_emb;
            const float* __restrict__ tB = (rB.x & (1u << 17)) ? entity_emb : user_emb;
            const float4 eA = *(const float4*)(tA + (size_t)(rA.x & 0x1FFFFu) * DIM + sub * 4);
            const float4 eB = *(const float4*)(tB + (size_t)(rB.x & 0x1FFFFu) * DIM + sub * 4);
            float vA = __uint_as_float(rA.y);
            float vB = __uint_as_float(rB.y);
            ax0 += vA * eA.x; ay0 += vA * eA.y; az0 += vA * eA.z; aw0 += vA * eA.w;
            ax1 += vB * eB.x; ay1 += vB * eB.y; az1 += vB * eB.z; aw1 += vB * eB.w;
        }
        for (; i < cnt; i += 4) {
            int j = i + grp;
            bool valid = j < cnt;
            uint2 r = srec[rb + (valid ? j : cnt - 1)];
            const float* __restrict__ tb = (r.x & (1u << 17)) ? entity_emb : user_emb;
            const float4 e = *(const float4*)(tb + (size_t)(r.x & 0x1FFFFu) * DIM + sub * 4);
            float v = valid ? __uint_as_float(r.y) : 0.f;
            ax0 += v * e.x; ay0 += v * e.y; az0 += v * e.z; aw0 += v * e.w;
        }

        ax0 += ax1; ay0 += ay1; az0 += az1; aw0 += aw1;
        ax0 += __shfl_xor(ax0, 16, 64); ay0 += __shfl_xor(ay0, 16, 64);
        az0 += __shfl_xor(az0, 16, 64); aw0 += __shfl_xor(aw0, 16, 64);
        ax0 += __shfl_xor(ax0, 32, 64); ay0 += __shfl_xor(ay0, 32, 64);
        az0 += __shfl_xor(az0, 32, 64); aw0 += __shfl_xor(aw0, 32, 64);

        if (grp == 0 && bucket < nb) {
            float4 res = make_float4(ax0, ay0, az0, aw0);
            *(float4*)(out + (size_t)bucket * DIM + sub * 4) = res;
        }
    }
}

// pass3: direct atomics for overflow partitions (normally zero work)
__global__ void pass3_ovf(const uint2* __restrict__ payload,
                          const int* __restrict__ poffs,
                          const int* __restrict__ ovfcnt,
                          const int* __restrict__ ovflist,
                          const float* __restrict__ user_emb,
                          const float* __restrict__ entity_emb,
                          float* __restrict__ out) {
    int no = *ovfcnt;
    for (int o = 0; o < no; ++o) {
        int p = ovflist[o];
        int beg = poffs[p];
        int n = poffs[p + 1] - beg;
        for (int j = blockIdx.x * blockDim.x + threadIdx.x; j < n * 16;
             j += gridDim.x * blockDim.x) {
            uint2 rec = payload[(size_t)beg + (j >> 4)];
            int d4 = (j & 15) * 4;
            const float* tab = (rec.x & (1u << 17)) ? entity_emb : user_emb;
            float v = __uint_as_float(rec.y);
            int bucket = (p << PBITS) | (int)((rec.x >> 18) & (PART_BUCKETS - 1));
            const float* src = tab + (size_t)(rec.x & 0x1FFFFu) * DIM + d4;
            float* dst = out + (size_t)bucket * DIM + d4;
            for (int d = 0; d < 4; ++d) atomicAdd(&dst[d], v * src[d]);
        }
    }
}

extern "C" void kernel_launch(void* const* d_in, const int* in_sizes, int n_in,
                              void* d_out, int out_size, void* d_ws, size_t ws_size,
                              hipStream_t stream) {
    const float* user_emb   = (const float*)d_in[0];  // [n_users, 64]
    const float* entity_emb = (const float*)d_in[1];  // [n_entities, 64]
    const int*   rows       = (const int*)d_in[2];
    const int*   cols       = (const int*)d_in[3];
    const float* vals       = (const float*)d_in[4];
    int nnz = in_sizes[2];
    int nu  = in_sizes[0] / DIM;   // 100000
    int ne  = in_sizes[1] / DIM;   // 50000
    int nb  = ne + nu;             // 150000 buckets
    int npart = (nb + PART_BUCKETS - 1) / PART_BUCKETS;   // 2344

    float* out = (float*)d_out;

    // ws (ints): pcnt[npart] | poffs[npart+1] | pcursor[npart] | ovfcnt[1]
    //          | ovflist[npart] | pad | payload[2*nnz]*8B
    size_t n_ints = (size_t)npart * 4 + 2;
    size_t pay_off_ints = (n_ints + 1) & ~(size_t)1;
    size_t need = pay_off_ints * 4 + (size_t)2 * nnz * 8;

    if (ws_size < need || npart > NPART_MAX || nu > 131072 || ne > 131072) {
        float* entity_agg = out;
        float* user_agg   = out + (size_t)ne * DIM;
        hipMemsetAsync(d_out, 0, (size_t)out_size * sizeof(float), stream);
        long long total = (long long)nnz * DIM;
        int block = 256;
        long long grid = (total + block - 1) / block;
        coo_scatter_kernel<<<(int)grid, block, 0, stream>>>(
            user_emb, entity_emb, rows, cols, vals, entity_agg, user_agg, nnz);
        return;
    }

    int*   pcnt    = (int*)d_ws;
    int*   poffs   = pcnt + npart;           // npart+1
    int*   pcursor = poffs + npart + 1;
    int*   ovfcnt  = pcursor + npart;        // 1
    int*   ovflist = ovfcnt + 1;             // npart
    uint2* payload = (uint2*)((int*)d_ws + pay_off_ints);

    hipMemsetAsync(pcnt, 0, (size_t)npart * sizeof(int), stream);

    pass0_hist<<<512, 256, 0, stream>>>(rows, cols, pcnt, ne, nnz, npart);
    scan_parts<<<1, 256, 0, stream>>>(pcnt, poffs, pcursor, ovfcnt, npart);
    int g1 = (nnz + EPB - 1) / EPB;
    pass1_part<<<g1, 256, 0, stream>>>(rows, cols, vals, pcursor, payload, ne, nnz, npart);
    sort_agg<<<npart, 256, 0, stream>>>(user_emb, entity_emb, payload, poffs,
                                        ovfcnt, ovflist, out, nb);
    pass3_ovf<<<64, 256, 0, stream>>>(payload, poffs, ovfcnt, ovflist,
                                      user_emb, entity_emb, out);
}

// Round 13
// 230.299 us; speedup vs baseline: 1.0475x; 1.0475x over previous
//
#include <hip/hip_runtime.h>

#define DIM 64
#define PBITS 6
#define PART_BUCKETS 64       // buckets per partition
#define NPART_MAX 2368        // >= ceil(150016/64)=2344
#define EPT 32                // edges per thread, pass1
#define EPB (EPT * 256)       // 8192 edges per block, pass1
#define CAP 3072              // max records per partition (avg 2560 entity, +10 sigma)

// ---------------- fallback (round-1) atomic kernel ----------------
__global__ void coo_scatter_kernel(const float* __restrict__ user_emb,
                                   const float* __restrict__ entity_emb,
                                   const int* __restrict__ rows,
                                   const int* __restrict__ cols,
                                   const float* __restrict__ vals,
                                   float* __restrict__ entity_agg,
                                   float* __restrict__ user_agg,
                                   int nnz) {
    long long tid = (long long)blockIdx.x * blockDim.x + threadIdx.x;
    long long total = (long long)nnz * DIM;
    if (tid >= total) return;
    int edge = (int)(tid >> 6);
    int d = (int)(tid & 63);
    int r = rows[edge];
    int c = cols[edge];
    float v = vals[edge];
    atomicAdd(&entity_agg[c * DIM + d], v * user_emb[r * DIM + d]);
    atomicAdd(&user_agg[r * DIM + d], v * entity_emb[c * DIM + d]);
}

// record: uint2 { meta, valbits }; meta = (local6<<18) | (side<<17) | src
// bucket = partition*64 + local6. side 0: gather user_emb; side 1: entity_emb.

// pass0: per-partition histogram (LDS-staged)
__global__ __launch_bounds__(256) void pass0_hist(const int* __restrict__ rows,
                                                  const int* __restrict__ cols,
                                                  int* __restrict__ pcnt,
                                                  int ne, int nnz, int npart) {
    __shared__ int h[NPART_MAX];
    for (int t = threadIdx.x; t < npart; t += 256) h[t] = 0;
    __syncthreads();
    for (int i = blockIdx.x * blockDim.x + threadIdx.x; i < nnz;
         i += gridDim.x * blockDim.x) {
        int c = cols[i];
        int r = rows[i];
        atomicAdd(&h[c >> PBITS], 1);
        atomicAdd(&h[(ne + r) >> PBITS], 1);
    }
    __syncthreads();
    for (int t = threadIdx.x; t < npart; t += 256)
        if (h[t]) atomicAdd(&pcnt[t], h[t]);
}

// scan over npart partition counts (single block, parallel)
__global__ __launch_bounds__(256) void scan_parts(const int* __restrict__ pcnt,
                                                  int* __restrict__ poffs,
                                                  int* __restrict__ pcursor,
                                                  int* __restrict__ ovfcnt,
                                                  int npart) {
    __shared__ int sh[256];
    int t = threadIdx.x;
    int local[10];
    int s = 0;
#pragma unroll
    for (int j = 0; j < 10; ++j) {
        int idx = t * 10 + j;
        local[j] = (idx < npart) ? pcnt[idx] : 0;
        s += local[j];
    }
    sh[t] = s;
    for (int off = 1; off < 256; off <<= 1) {
        __syncthreads();
        int tmp = (t >= off) ? sh[t - off] : 0;
        __syncthreads();
        sh[t] += tmp;
    }
    __syncthreads();
    int run = sh[t] - s;   // exclusive prefix
#pragma unroll
    for (int j = 0; j < 10; ++j) {
        int idx = t * 10 + j;
        if (idx < npart) {
            poffs[idx] = run;
            pcursor[idx] = run;
            run += local[j];
        }
    }
    if (t == 255) poffs[npart] = sh[255];
    if (t == 0) *ovfcnt = 0;
}

// pass1: two sweeps over this block's edges. Sweep A: LDS histogram.
// Claim one contiguous global chunk per (block, partition). Sweep B:
// rebuild record on the fly (L2-hot re-read) and store at rank.
// All writers of a chunk are one block -> mostly single-L2 full lines.
__global__ __launch_bounds__(256) void pass1_part(const int* __restrict__ rows,
                                                  const int* __restrict__ cols,
                                                  const float* __restrict__ vals,
                                                  int* __restrict__ pcursor,
                                                  uint2* __restrict__ payload,
                                                  int ne, int nnz, int npart) {
    __shared__ int hist[NPART_MAX];
    __shared__ int cur[NPART_MAX];
    __shared__ int gbase[NPART_MAX];
    for (int t = threadIdx.x; t < npart; t += 256) { hist[t] = 0; cur[t] = 0; }
    __syncthreads();

    int base = blockIdx.x * EPB;
#pragma unroll 4
    for (int k = 0; k < EPT; ++k) {
        int i = base + threadIdx.x + k * 256;
        if (i < nnz) {
            atomicAdd(&hist[cols[i] >> PBITS], 1);
            atomicAdd(&hist[(ne + rows[i]) >> PBITS], 1);
        }
    }
    __syncthreads();
    for (int p = threadIdx.x; p < npart; p += 256) {
        int c_ = hist[p];
        if (c_) gbase[p] = atomicAdd(&pcursor[p], c_);
    }
    __syncthreads();
#pragma unroll 4
    for (int k = 0; k < EPT; ++k) {
        int i = base + threadIdx.x + k * 256;
        if (i < nnz) {
            int r = rows[i];
            int c = cols[i];
            unsigned vb = __float_as_uint(vals[i]);
            int b2 = ne + r;
            int p1 = c >> PBITS;
            int p2 = b2 >> PBITS;
            int rank1 = atomicAdd(&cur[p1], 1);
            payload[(size_t)gbase[p1] + rank1] =
                make_uint2(((unsigned)(c & (PART_BUCKETS - 1)) << 18) | (unsigned)r, vb);
            int rank2 = atomicAdd(&cur[p2], 1);
            payload[(size_t)gbase[p2] + rank2] =
                make_uint2(((unsigned)(b2 & (PART_BUCKETS - 1)) << 18) | (1u << 17) | (unsigned)c, vb);
        }
    }
}

// fused sort+agg: one block per partition. Load records to regs, counting
// sort into LDS, then each wave aggregates 16 buckets straight from LDS.
// CAP=3072 keeps LDS at ~25 KB -> 6 blocks/CU -> 75% occupancy.
__global__ __launch_bounds__(256) void sort_agg(const float* __restrict__ user_emb,
                                                const float* __restrict__ entity_emb,
                                                const uint2* __restrict__ payload,
                                                const int* __restrict__ poffs,
                                                int* __restrict__ ovfcnt,
                                                int* __restrict__ ovflist,
                                                float* __restrict__ out,
                                                int nb) {
    __shared__ uint2 srec[CAP];                       // 24 KB sorted records
    __shared__ int h[PART_BUCKETS], sc[PART_BUCKETS], cu[PART_BUCKETS];
    int p = blockIdx.x;
    int beg = poffs[p];
    int n = poffs[p + 1] - beg;
    int t = threadIdx.x;
    if (t < PART_BUCKETS) h[t] = 0;
    __syncthreads();

    if (n > CAP) {   // ~10 sigma; zero rows, defer to pass3 atomics
        if (t == 0) {
            int o = atomicAdd(ovfcnt, 1);
            ovflist[o] = p;
        }
        int b0 = p << PBITS;
        for (int e = t; e < PART_BUCKETS * DIM; e += 256) {
            int b = b0 + (e >> 6);
            if (b < nb) out[(size_t)b * DIM + (e & 63)] = 0.f;
        }
        return;
    }

    uint2 rec[CAP / 256];
#pragma unroll
    for (int k = 0; k < CAP / 256; ++k) {
        int idx = t + k * 256;
        if (idx < n) {
            rec[k] = payload[(size_t)beg + idx];
            atomicAdd(&h[(rec[k].x >> 18) & (PART_BUCKETS - 1)], 1);
        }
    }
    __syncthreads();
    if (t == 0) {
        int run = 0;
#pragma unroll
        for (int j = 0; j < PART_BUCKETS; ++j) { sc[j] = run; cu[j] = run; run += h[j]; }
    }
    __syncthreads();
#pragma unroll
    for (int k = 0; k < CAP / 256; ++k) {
        int idx = t + k * 256;
        if (idx < n) {
            int b = (rec[k].x >> 18) & (PART_BUCKETS - 1);
            int rank = atomicAdd(&cu[b], 1);
            srec[rank] = rec[k];
        }
    }
    __syncthreads();

    // phase 2: wave w aggregates buckets [w*16, w*16+16)
    int wid = t >> 6;
    int lane = t & 63;
    int grp = lane >> 4;      // which record of the quad
    int sub = lane & 15;      // float4 slot within the row

    for (int bi = 0; bi < 16; ++bi) {
        int lb = wid * 16 + bi;
        int bucket = (p << PBITS) + lb;
        int rb = sc[lb];
        int cnt = h[lb];

        float ax0 = 0.f, ay0 = 0.f, az0 = 0.f, aw0 = 0.f;
        float ax1 = 0.f, ay1 = 0.f, az1 = 0.f, aw1 = 0.f;
        float ax2 = 0.f, ay2 = 0.f, az2 = 0.f, aw2 = 0.f;
        float ax3 = 0.f, ay3 = 0.f, az3 = 0.f, aw3 = 0.f;

        int i = 0;
        for (; i + 16 <= cnt; i += 16) {
            uint2 r0 = srec[rb + i + grp];
            uint2 r1 = srec[rb + i + 4 + grp];
            uint2 r2 = srec[rb + i + 8 + grp];
            uint2 r3 = srec[rb + i + 12 + grp];
            const float* __restrict__ t0 = (r0.x & (1u << 17)) ? entity_emb : user_emb;
            const float* __restrict__ t1 = (r1.x & (1u << 17)) ? entity_emb : user_emb;
            const float* __restrict__ t2 = (r2.x & (1u << 17)) ? entity_emb : user_emb;
            const float* __restrict__ t3 = (r3.x & (1u << 17)) ? entity_emb : user_emb;
            const float4 e0 = *(const float4*)(t0 + (size_t)(r0.x & 0x1FFFFu) * DIM + sub * 4);
            const float4 e1 = *(const float4*)(t1 + (size_t)(r1.x & 0x1FFFFu) * DIM + sub * 4);
            const float4 e2 = *(const float4*)(t2 + (size_t)(r2.x & 0x1FFFFu) * DIM + sub * 4);
            const float4 e3 = *(const float4*)(t3 + (size_t)(r3.x & 0x1FFFFu) * DIM + sub * 4);
            float v0 = __uint_as_float(r0.y);
            float v1 = __uint_as_float(r1.y);
            float v2 = __uint_as_float(r2.y);
            float v3 = __uint_as_float(r3.y);
            ax0 += v0 * e0.x; ay0 += v0 * e0.y; az0 += v0 * e0.z; aw0 += v0 * e0.w;
            ax1 += v1 * e1.x; ay1 += v1 * e1.y; az1 += v1 * e1.z; aw1 += v1 * e1.w;
            ax2 += v2 * e2.x; ay2 += v2 * e2.y; az2 += v2 * e2.z; aw2 += v2 * e2.w;
            ax3 += v3 * e3.x; ay3 += v3 * e3.y; az3 += v3 * e3.z; aw3 += v3 * e3.w;
        }
        for (; i + 8 <= cnt; i += 8) {
            uint2 rA = srec[rb + i + grp];
            uint2 rB = srec[rb + i + 4 + grp];
            const float* __restrict__ tA = (rA.x & (1u << 17)) ? entity_emb : user_emb;
            const float* __restrict__ tB = (rB.x & (1u << 17)) ? entity_emb : user_emb;
            const float4 eA = *(const float4*)(tA + (size_t)(rA.x & 0x1FFFFu) * DIM + sub * 4);
            const float4 eB = *(const float4*)(tB + (size_t)(rB.x & 0x1FFFFu) * DIM + sub * 4);
            float vA = __uint_as_float(rA.y);
            float vB = __uint_as_float(rB.y);
            ax0 += vA * eA.x; ay0 += vA * eA.y; az0 += vA * eA.z; aw0 += vA * eA.w;
            ax1 += vB * eB.x; ay1 += vB * eB.y; az1 += vB * eB.z; aw1 += vB * eB.w;
        }
        for (; i < cnt; i += 4) {
            int j = i + grp;
            bool valid = j < cnt;
            uint2 r = srec[rb + (valid ? j : cnt - 1)];
            const float* __restrict__ tb = (r.x & (1u << 17)) ? entity_emb : user_emb;
            const float4 e = *(const float4*)(tb + (size_t)(r.x & 0x1FFFFu) * DIM + sub * 4);
            float v = valid ? __uint_as_float(r.y) : 0.f;
            ax0 += v * e.x; ay0 += v * e.y; az0 += v * e.z; aw0 += v * e.w;
        }

        ax0 += ax1 + ax2 + ax3; ay0 += ay1 + ay2 + ay3;
        az0 += az1 + az2 + az3; aw0 += aw1 + aw2 + aw3;
        ax0 += __shfl_xor(ax0, 16, 64); ay0 += __shfl_xor(ay0, 16, 64);
        az0 += __shfl_xor(az0, 16, 64); aw0 += __shfl_xor(aw0, 16, 64);
        ax0 += __shfl_xor(ax0, 32, 64); ay0 += __shfl_xor(ay0, 32, 64);
        az0 += __shfl_xor(az0, 32, 64); aw0 += __shfl_xor(aw0, 32, 64);

        if (grp == 0 && bucket < nb) {
            float4 res = make_float4(ax0, ay0, az0, aw0);
            *(float4*)(out + (size_t)bucket * DIM + sub * 4) = res;
        }
    }
}

// pass3: direct atomics for overflow partitions (normally zero work)
__global__ void pass3_ovf(const uint2* __restrict__ payload,
                          const int* __restrict__ poffs,
                          const int* __restrict__ ovfcnt,
                          const int* __restrict__ ovflist,
                          const float* __restrict__ user_emb,
                          const float* __restrict__ entity_emb,
                          float* __restrict__ out) {
    int no = *ovfcnt;
    for (int o = 0; o < no; ++o) {
        int p = ovflist[o];
        int beg = poffs[p];
        int n = poffs[p + 1] - beg;
        for (int j = blockIdx.x * blockDim.x + threadIdx.x; j < n * 16;
             j += gridDim.x * blockDim.x) {
            uint2 rec = payload[(size_t)beg + (j >> 4)];
            int d4 = (j & 15) * 4;
            const float* tab = (rec.x & (1u << 17)) ? entity_emb : user_emb;
            float v = __uint_as_float(rec.y);
            int bucket = (p << PBITS) | (int)((rec.x >> 18) & (PART_BUCKETS - 1));
            const float* src = tab + (size_t)(rec.x & 0x1FFFFu) * DIM + d4;
            float* dst = out + (size_t)bucket * DIM + d4;
            for (int d = 0; d < 4; ++d) atomicAdd(&dst[d], v * src[d]);
        }
    }
}

extern "C" void kernel_launch(void* const* d_in, const int* in_sizes, int n_in,
                              void* d_out, int out_size, void* d_ws, size_t ws_size,
                              hipStream_t stream) {
    const float* user_emb   = (const float*)d_in[0];  // [n_users, 64]
    const float* entity_emb = (const float*)d_in[1];  // [n_entities, 64]
    const int*   rows       = (const int*)d_in[2];
    const int*   cols       = (const int*)d_in[3];
    const float* vals       = (const float*)d_in[4];
    int nnz = in_sizes[2];
    int nu  = in_sizes[0] / DIM;   // 100000
    int ne  = in_sizes[1] / DIM;   // 50000
    int nb  = ne + nu;             // 150000 buckets
    int npart = (nb + PART_BUCKETS - 1) / PART_BUCKETS;   // 2344

    float* out = (float*)d_out;

    // ws (ints): pcnt[npart] | poffs[npart+1] | pcursor[npart] | ovfcnt[1]
    //          | ovflist[npart] | pad | payload[2*nnz]*8B
    size_t n_ints = (size_t)npart * 4 + 2;
    size_t pay_off_ints = (n_ints + 1) & ~(size_t)1;
    size_t need = pay_off_ints * 4 + (size_t)2 * nnz * 8;

    if (ws_size < need || npart > NPART_MAX || nu > 131072 || ne > 131072) {
        float* entity_agg = out;
        float* user_agg   = out + (size_t)ne * DIM;
        hipMemsetAsync(d_out, 0, (size_t)out_size * sizeof(float), stream);
        long long total = (long long)nnz * DIM;
        int block = 256;
        long long grid = (total + block - 1) / block;
        coo_scatter_kernel<<<(int)grid, block, 0, stream>>>(
            user_emb, entity_emb, rows, cols, vals, entity_agg, user_agg, nnz);
        return;
    }

    int*   pcnt    = (int*)d_ws;
    int*   poffs   = pcnt + npart;           // npart+1
    int*   pcursor = poffs + npart + 1;
    int*   ovfcnt  = pcursor + npart;        // 1
    int*   ovflist = ovfcnt + 1;             // npart
    uint2* payload = (uint2*)((int*)d_ws + pay_off_ints);

    hipMemsetAsync(pcnt, 0, (size_t)npart * sizeof(int), stream);

    pass0_hist<<<512, 256, 0, stream>>>(rows, cols, pcnt, ne, nnz, npart);
    scan_parts<<<1, 256, 0, stream>>>(pcnt, poffs, pcursor, ovfcnt, npart);
    int g1 = (nnz + EPB - 1) / EPB;
    pass1_part<<<g1, 256, 0, stream>>>(rows, cols, vals, pcursor, payload, ne, nnz, npart);
    sort_agg<<<npart, 256, 0, stream>>>(user_emb, entity_emb, payload, poffs,
                                        ovfcnt, ovflist, out, nb);
    pass3_ovf<<<64, 256, 0, stream>>>(payload, poffs, ovfcnt, ovflist,
                                      user_emb, entity_emb, out);
}

// Round 14
// 210.152 us; speedup vs baseline: 1.1479x; 1.0959x over previous
//
#include <hip/hip_runtime.h>

#define DIM 64
#define PBITS 6
#define PART_BUCKETS 64       // buckets per partition
#define NPART_MAX 2368        // >= ceil(150016/64)=2344
#define EPT 8                 // edges per thread, pass1 (1024 threads)
#define EPB (EPT * 1024)      // 8192 edges per block, pass1
#define CAP 2944              // max records per partition (avg 2560 entity, +7.5 sigma)
#define RECK ((CAP + 255) / 256)

// ---------------- fallback (round-1) atomic kernel ----------------
__global__ void coo_scatter_kernel(const float* __restrict__ user_emb,
                                   const float* __restrict__ entity_emb,
                                   const int* __restrict__ rows,
                                   const int* __restrict__ cols,
                                   const float* __restrict__ vals,
                                   float* __restrict__ entity_agg,
                                   float* __restrict__ user_agg,
                                   int nnz) {
    long long tid = (long long)blockIdx.x * blockDim.x + threadIdx.x;
    long long total = (long long)nnz * DIM;
    if (tid >= total) return;
    int edge = (int)(tid >> 6);
    int d = (int)(tid & 63);
    int r = rows[edge];
    int c = cols[edge];
    float v = vals[edge];
    atomicAdd(&entity_agg[c * DIM + d], v * user_emb[r * DIM + d]);
    atomicAdd(&user_agg[r * DIM + d], v * entity_emb[c * DIM + d]);
}

// record: uint2 { meta, valbits }; meta = (local6<<18) | (side<<17) | src
// bucket = partition*64 + local6. side 0: gather user_emb; side 1: entity_emb.

// pass0: per-partition histogram (LDS-staged), 1024 threads for occupancy
__global__ __launch_bounds__(1024) void pass0_hist(const int* __restrict__ rows,
                                                   const int* __restrict__ cols,
                                                   int* __restrict__ pcnt,
                                                   int ne, int nnz, int npart) {
    __shared__ int h[NPART_MAX];
    for (int t = threadIdx.x; t < npart; t += 1024) h[t] = 0;
    __syncthreads();
    for (int i = blockIdx.x * blockDim.x + threadIdx.x; i < nnz;
         i += gridDim.x * blockDim.x) {
        int c = cols[i];
        int r = rows[i];
        atomicAdd(&h[c >> PBITS], 1);
        atomicAdd(&h[(ne + r) >> PBITS], 1);
    }
    __syncthreads();
    for (int t = threadIdx.x; t < npart; t += 1024)
        if (h[t]) atomicAdd(&pcnt[t], h[t]);
}

// scan over npart partition counts (single block, parallel)
__global__ __launch_bounds__(256) void scan_parts(const int* __restrict__ pcnt,
                                                  int* __restrict__ poffs,
                                                  int* __restrict__ pcursor,
                                                  int* __restrict__ ovfcnt,
                                                  int npart) {
    __shared__ int sh[256];
    int t = threadIdx.x;
    int local[10];
    int s = 0;
#pragma unroll
    for (int j = 0; j < 10; ++j) {
        int idx = t * 10 + j;
        local[j] = (idx < npart) ? pcnt[idx] : 0;
        s += local[j];
    }
    sh[t] = s;
    for (int off = 1; off < 256; off <<= 1) {
        __syncthreads();
        int tmp = (t >= off) ? sh[t - off] : 0;
        __syncthreads();
        sh[t] += tmp;
    }
    __syncthreads();
    int run = sh[t] - s;   // exclusive prefix
#pragma unroll
    for (int j = 0; j < 10; ++j) {
        int idx = t * 10 + j;
        if (idx < npart) {
            poffs[idx] = run;
            pcursor[idx] = run;
            run += local[j];
        }
    }
    if (t == 255) poffs[npart] = sh[255];
    if (t == 0) *ovfcnt = 0;
}

// pass1: two sweeps over this block's edges. Sweep A: LDS histogram.
// Claim one contiguous global chunk per (block, partition). Sweep B:
// rebuild record on the fly (L2-hot re-read) and store at rank.
// 1024 threads (16 waves/CU) for latency hiding; EPB unchanged so chunk
// sizes (write locality) unchanged.
__global__ __launch_bounds__(1024) void pass1_part(const int* __restrict__ rows,
                                                   const int* __restrict__ cols,
                                                   const float* __restrict__ vals,
                                                   int* __restrict__ pcursor,
                                                   uint2* __restrict__ payload,
                                                   int ne, int nnz, int npart) {
    __shared__ int hist[NPART_MAX];
    __shared__ int cur[NPART_MAX];
    __shared__ int gbase[NPART_MAX];
    for (int t = threadIdx.x; t < npart; t += 1024) { hist[t] = 0; cur[t] = 0; }
    __syncthreads();

    int base = blockIdx.x * EPB;
#pragma unroll
    for (int k = 0; k < EPT; ++k) {
        int i = base + threadIdx.x + k * 1024;
        if (i < nnz) {
            atomicAdd(&hist[cols[i] >> PBITS], 1);
            atomicAdd(&hist[(ne + rows[i]) >> PBITS], 1);
        }
    }
    __syncthreads();
    for (int p = threadIdx.x; p < npart; p += 1024) {
        int c_ = hist[p];
        if (c_) gbase[p] = atomicAdd(&pcursor[p], c_);
    }
    __syncthreads();
#pragma unroll
    for (int k = 0; k < EPT; ++k) {
        int i = base + threadIdx.x + k * 1024;
        if (i < nnz) {
            int r = rows[i];
            int c = cols[i];
            unsigned vb = __float_as_uint(vals[i]);
            int b2 = ne + r;
            int p1 = c >> PBITS;
            int p2 = b2 >> PBITS;
            int rank1 = atomicAdd(&cur[p1], 1);
            payload[(size_t)gbase[p1] + rank1] =
                make_uint2(((unsigned)(c & (PART_BUCKETS - 1)) << 18) | (unsigned)r, vb);
            int rank2 = atomicAdd(&cur[p2], 1);
            payload[(size_t)gbase[p2] + rank2] =
                make_uint2(((unsigned)(b2 & (PART_BUCKETS - 1)) << 18) | (1u << 17) | (unsigned)c, vb);
        }
    }
}

// fused sort+agg: one block per partition. Load records to regs, counting
// sort into LDS, then each wave aggregates 16 buckets straight from LDS.
// CAP=2944 keeps LDS at ~24.3 KB -> 5 blocks/CU.
__global__ __launch_bounds__(256) void sort_agg(const float* __restrict__ user_emb,
                                                const float* __restrict__ entity_emb,
                                                const uint2* __restrict__ payload,
                                                const int* __restrict__ poffs,
                                                int* __restrict__ ovfcnt,
                                                int* __restrict__ ovflist,
                                                float* __restrict__ out,
                                                int nb) {
    __shared__ uint2 srec[CAP];                       // 23 KB sorted records
    __shared__ int h[PART_BUCKETS], sc[PART_BUCKETS], cu[PART_BUCKETS];
    int p = blockIdx.x;
    int beg = poffs[p];
    int n = poffs[p + 1] - beg;
    int t = threadIdx.x;
    if (t < PART_BUCKETS) h[t] = 0;
    __syncthreads();

    if (n > CAP) {   // ~7.5 sigma; zero rows, defer to pass3 atomics
        if (t == 0) {
            int o = atomicAdd(ovfcnt, 1);
            ovflist[o] = p;
        }
        int b0 = p << PBITS;
        for (int e = t; e < PART_BUCKETS * DIM; e += 256) {
            int b = b0 + (e >> 6);
            if (b < nb) out[(size_t)b * DIM + (e & 63)] = 0.f;
        }
        return;
    }

    uint2 rec[RECK];
#pragma unroll
    for (int k = 0; k < RECK; ++k) {
        int idx = t + k * 256;
        if (idx < n) {
            rec[k] = payload[(size_t)beg + idx];
            atomicAdd(&h[(rec[k].x >> 18) & (PART_BUCKETS - 1)], 1);
        }
    }
    __syncthreads();
    if (t == 0) {
        int run = 0;
#pragma unroll
        for (int j = 0; j < PART_BUCKETS; ++j) { sc[j] = run; cu[j] = run; run += h[j]; }
    }
    __syncthreads();
#pragma unroll
    for (int k = 0; k < RECK; ++k) {
        int idx = t + k * 256;
        if (idx < n) {
            int b = (rec[k].x >> 18) & (PART_BUCKETS - 1);
            int rank = atomicAdd(&cu[b], 1);
            srec[rank] = rec[k];
        }
    }
    __syncthreads();

    // phase 2: wave w aggregates buckets [w*16, w*16+16)
    int wid = t >> 6;
    int lane = t & 63;
    int grp = lane >> 4;      // which record of the quad
    int sub = lane & 15;      // float4 slot within the row

    for (int bi = 0; bi < 16; ++bi) {
        int lb = wid * 16 + bi;
        int bucket = (p << PBITS) + lb;
        int rb = sc[lb];
        int cnt = h[lb];

        float ax0 = 0.f, ay0 = 0.f, az0 = 0.f, aw0 = 0.f;
        float ax1 = 0.f, ay1 = 0.f, az1 = 0.f, aw1 = 0.f;
        float ax2 = 0.f, ay2 = 0.f, az2 = 0.f, aw2 = 0.f;
        float ax3 = 0.f, ay3 = 0.f, az3 = 0.f, aw3 = 0.f;

        int i = 0;
        for (; i + 16 <= cnt; i += 16) {
            uint2 r0 = srec[rb + i + grp];
            uint2 r1 = srec[rb + i + 4 + grp];
            uint2 r2 = srec[rb + i + 8 + grp];
            uint2 r3 = srec[rb + i + 12 + grp];
            const float* __restrict__ t0 = (r0.x & (1u << 17)) ? entity_emb : user_emb;
            const float* __restrict__ t1 = (r1.x & (1u << 17)) ? entity_emb : user_emb;
            const float* __restrict__ t2 = (r2.x & (1u << 17)) ? entity_emb : user_emb;
            const float* __restrict__ t3 = (r3.x & (1u << 17)) ? entity_emb : user_emb;
            const float4 e0 = *(const float4*)(t0 + (size_t)(r0.x & 0x1FFFFu) * DIM + sub * 4);
            const float4 e1 = *(const float4*)(t1 + (size_t)(r1.x & 0x1FFFFu) * DIM + sub * 4);
            const float4 e2 = *(const float4*)(t2 + (size_t)(r2.x & 0x1FFFFu) * DIM + sub * 4);
            const float4 e3 = *(const float4*)(t3 + (size_t)(r3.x & 0x1FFFFu) * DIM + sub * 4);
            float v0 = __uint_as_float(r0.y);
            float v1 = __uint_as_float(r1.y);
            float v2 = __uint_as_float(r2.y);
            float v3 = __uint_as_float(r3.y);
            ax0 += v0 * e0.x; ay0 += v0 * e0.y; az0 += v0 * e0.z; aw0 += v0 * e0.w;
            ax1 += v1 * e1.x; ay1 += v1 * e1.y; az1 += v1 * e1.z; aw1 += v1 * e1.w;
            ax2 += v2 * e2.x; ay2 += v2 * e2.y; az2 += v2 * e2.z; aw2 += v2 * e2.w;
            ax3 += v3 * e3.x; ay3 += v3 * e3.y; az3 += v3 * e3.z; aw3 += v3 * e3.w;
        }
        for (; i + 8 <= cnt; i += 8) {
            uint2 rA = srec[rb + i + grp];
            uint2 rB = srec[rb + i + 4 + grp];
            const float* __restrict__ tA = (rA.x & (1u << 17)) ? entity_emb : user_emb;
            const float* __restrict__ tB = (rB.x & (1u << 17)) ? entity_emb : user_emb;
            const float4 eA = *(const float4*)(tA + (size_t)(rA.x & 0x1FFFFu) * DIM + sub * 4);
            const float4 eB = *(const float4*)(tB + (size_t)(rB.x & 0x1FFFFu) * DIM + sub * 4);
            float vA = __uint_as_float(rA.y);
            float vB = __uint_as_float(rB.y);
            ax0 += vA * eA.x; ay0 += vA * eA.y; az0 += vA * eA.z; aw0 += vA * eA.w;
            ax1 += vB * eB.x; ay1 += vB * eB.y; az1 += vB * eB.z; aw1 += vB * eB.w;
        }
        for (; i < cnt; i += 4) {
            int j = i + grp;
            bool valid = j < cnt;
            uint2 r = srec[rb + (valid ? j : cnt - 1)];
            const float* __restrict__ tb = (r.x & (1u << 17)) ? entity_emb : user_emb;
            const float4 e = *(const float4*)(tb + (size_t)(r.x & 0x1FFFFu) * DIM + sub * 4);
            float v = valid ? __uint_as_float(r.y) : 0.f;
            ax0 += v * e.x; ay0 += v * e.y; az0 += v * e.z; aw0 += v * e.w;
        }

        ax0 += ax1 + ax2 + ax3; ay0 += ay1 + ay2 + ay3;
        az0 += az1 + az2 + az3; aw0 += aw1 + aw2 + aw3;
        ax0 += __shfl_xor(ax0, 16, 64); ay0 += __shfl_xor(ay0, 16, 64);
        az0 += __shfl_xor(az0, 16, 64); aw0 += __shfl_xor(aw0, 16, 64);
        ax0 += __shfl_xor(ax0, 32, 64); ay0 += __shfl_xor(ay0, 32, 64);
        az0 += __shfl_xor(az0, 32, 64); aw0 += __shfl_xor(aw0, 32, 64);

        if (grp == 0 && bucket < nb) {
            float4 res = make_float4(ax0, ay0, az0, aw0);
            *(float4*)(out + (size_t)bucket * DIM + sub * 4) = res;
        }
    }
}

// pass3: direct atomics for overflow partitions (normally zero work)
__global__ void pass3_ovf(const uint2* __restrict__ payload,
                          const int* __restrict__ poffs,
                          const int* __restrict__ ovfcnt,
                          const int* __restrict__ ovflist,
                          const float* __restrict__ user_emb,
                          const float* __restrict__ entity_emb,
                          float* __restrict__ out) {
    int no = *ovfcnt;
    for (int o = 0; o < no; ++o) {
        int p = ovflist[o];
        int beg = poffs[p];
        int n = poffs[p + 1] - beg;
        for (int j = blockIdx.x * blockDim.x + threadIdx.x; j < n * 16;
             j += gridDim.x * blockDim.x) {
            uint2 rec = payload[(size_t)beg + (j >> 4)];
            int d4 = (j & 15) * 4;
            const float* tab = (rec.x & (1u << 17)) ? entity_emb : user_emb;
            float v = __uint_as_float(rec.y);
            int bucket = (p << PBITS) | (int)((rec.x >> 18) & (PART_BUCKETS - 1));
            const float* src = tab + (size_t)(rec.x & 0x1FFFFu) * DIM + d4;
            float* dst = out + (size_t)bucket * DIM + d4;
            for (int d = 0; d < 4; ++d) atomicAdd(&dst[d], v * src[d]);
        }
    }
}

extern "C" void kernel_launch(void* const* d_in, const int* in_sizes, int n_in,
                              void* d_out, int out_size, void* d_ws, size_t ws_size,
                              hipStream_t stream) {
    const float* user_emb   = (const float*)d_in[0];  // [n_users, 64]
    const float* entity_emb = (const float*)d_in[1];  // [n_entities, 64]
    const int*   rows       = (const int*)d_in[2];
    const int*   cols       = (const int*)d_in[3];
    const float* vals       = (const float*)d_in[4];
    int nnz = in_sizes[2];
    int nu  = in_sizes[0] / DIM;   // 100000
    int ne  = in_sizes[1] / DIM;   // 50000
    int nb  = ne + nu;             // 150000 buckets
    int npart = (nb + PART_BUCKETS - 1) / PART_BUCKETS;   // 2344

    float* out = (float*)d_out;

    // ws (ints): pcnt[npart] | poffs[npart+1] | pcursor[npart] | ovfcnt[1]
    //          | ovflist[npart] | pad | payload[2*nnz]*8B
    size_t n_ints = (size_t)npart * 4 + 2;
    size_t pay_off_ints = (n_ints + 1) & ~(size_t)1;
    size_t need = pay_off_ints * 4 + (size_t)2 * nnz * 8;

    if (ws_size < need || npart > NPART_MAX || nu > 131072 || ne > 131072) {
        float* entity_agg = out;
        float* user_agg   = out + (size_t)ne * DIM;
        hipMemsetAsync(d_out, 0, (size_t)out_size * sizeof(float), stream);
        long long total = (long long)nnz * DIM;
        int block = 256;
        long long grid = (total + block - 1) / block;
        coo_scatter_kernel<<<(int)grid, block, 0, stream>>>(
            user_emb, entity_emb, rows, cols, vals, entity_agg, user_agg, nnz);
        return;
    }

    int*   pcnt    = (int*)d_ws;
    int*   poffs   = pcnt + npart;           // npart+1
    int*   pcursor = poffs + npart + 1;
    int*   ovfcnt  = pcursor + npart;        // 1
    int*   ovflist = ovfcnt + 1;             // npart
    uint2* payload = (uint2*)((int*)d_ws + pay_off_ints);

    hipMemsetAsync(pcnt, 0, (size_t)npart * sizeof(int), stream);

    pass0_hist<<<256, 1024, 0, stream>>>(rows, cols, pcnt, ne, nnz, npart);
    scan_parts<<<1, 256, 0, stream>>>(pcnt, poffs, pcursor, ovfcnt, npart);
    int g1 = (nnz + EPB - 1) / EPB;
    pass1_part<<<g1, 1024, 0, stream>>>(rows, cols, vals, pcursor, payload, ne, nnz, npart);
    sort_agg<<<npart, 256, 0, stream>>>(user_emb, entity_emb, payload, poffs,
                                        ovfcnt, ovflist, out, nb);
    pass3_ovf<<<64, 256, 0, stream>>>(payload, poffs, ovfcnt, ovflist,
                                      user_emb, entity_emb, out);
}